// Round 1
// baseline (18.904 us; speedup 1.0000x reference)
//
#include <hip/hip_runtime.h>
#include <math.h>

#define H    1024
#define MAPD 2048

__device__ __forceinline__ float sigmoidf_(float x) {
    return 1.0f / (1.0f + expf(-x));
}

__device__ __forceinline__ float wave_reduce_sum(float v) {
#pragma unroll
    for (int off = 32; off >= 1; off >>= 1)
        v += __shfl_xor(v, off, 64);
    return v;
}

// Kernel 1: blocks 0..255 compute h_map (one wave per hidden j, rows i/g/o).
//           block 256 computes h_pts (input is only 4-wide).
// Writes final_in = [h_map | h_pts] contiguously into ws[0..2047].
__global__ __launch_bounds__(256) void k_first(
    const float* __restrict__ x,       // map [2048]
    const float* __restrict__ W,       // W_ih_map [4096][2048]
    const float* __restrict__ b_ih,    // [4096]
    const float* __restrict__ b_hh,    // [4096]
    const float* __restrict__ Wp,      // W_ih_pts [4096][4]
    const float* __restrict__ bp_ih,   // [4096]
    const float* __restrict__ bp_hh,   // [4096]
    const float* __restrict__ goal,    // [2]
    const float* __restrict__ cur,     // [2]
    float* __restrict__ fin)           // ws: [0..1023]=h_map, [1024..2047]=h_pts
{
    int b = blockIdx.x;
    if (b < 256) {
        int wave = threadIdx.x >> 6;
        int lane = threadIdx.x & 63;
        int j = b * 4 + wave;
        const float4* x4 = (const float4*)x;
        const float4* Wi = (const float4*)(W + (size_t)j * MAPD);
        const float4* Wg = (const float4*)(W + (size_t)(2 * H + j) * MAPD);
        const float4* Wo = (const float4*)(W + (size_t)(3 * H + j) * MAPD);
        float si = 0.f, sg = 0.f, so = 0.f;
#pragma unroll
        for (int it = 0; it < 8; ++it) {
            int idx = it * 64 + lane;  // float4 index, 512 per row
            float4 xv = x4[idx];
            float4 a = Wi[idx];
            si += a.x * xv.x + a.y * xv.y + a.z * xv.z + a.w * xv.w;
            float4 g = Wg[idx];
            sg += g.x * xv.x + g.y * xv.y + g.z * xv.z + g.w * xv.w;
            float4 o = Wo[idx];
            so += o.x * xv.x + o.y * xv.y + o.z * xv.z + o.w * xv.w;
        }
        si = wave_reduce_sum(si);
        sg = wave_reduce_sum(sg);
        so = wave_reduce_sum(so);
        if (lane == 0) {
            float gi = si + b_ih[j] + b_hh[j];
            float gg = sg + b_ih[2 * H + j] + b_hh[2 * H + j];
            float go = so + b_ih[3 * H + j] + b_hh[3 * H + j];
            float c = sigmoidf_(gi) * tanhf(gg);
            fin[j] = sigmoidf_(go) * tanhf(c);   // h_map[j]
        }
    } else {
        // points cell: points = [cur0, cur1, goal0, goal1]
        float p0 = cur[0], p1 = cur[1], p2 = goal[0], p3 = goal[1];
        const float4* Wp4 = (const float4*)Wp;  // row j = one float4
#pragma unroll
        for (int t = 0; t < 4; ++t) {
            int j = t * 256 + threadIdx.x;
            float4 wi = Wp4[j];
            float4 wg = Wp4[2 * H + j];
            float4 wo = Wp4[3 * H + j];
            float gi = wi.x * p0 + wi.y * p1 + wi.z * p2 + wi.w * p3 + bp_ih[j] + bp_hh[j];
            float gg = wg.x * p0 + wg.y * p1 + wg.z * p2 + wg.w * p3 + bp_ih[2 * H + j] + bp_hh[2 * H + j];
            float go = wo.x * p0 + wo.y * p1 + wo.z * p2 + wo.w * p3 + bp_ih[3 * H + j] + bp_hh[3 * H + j];
            float c = sigmoidf_(gi) * tanhf(gg);
            fin[H + j] = sigmoidf_(go) * tanhf(c);  // h_pts[j]
        }
    }
}

// Kernel 2: lstm1 cell on final_in (2048) -> h1 into ws[2048..3071]
__global__ __launch_bounds__(256) void k_lstm1(
    const float* __restrict__ fin,     // ws [2048]
    const float* __restrict__ W,       // W_ih_1 [4096][2048]
    const float* __restrict__ b_ih,
    const float* __restrict__ b_hh,
    float* __restrict__ h1)            // ws + 2048
{
    int wave = threadIdx.x >> 6;
    int lane = threadIdx.x & 63;
    int j = blockIdx.x * 4 + wave;
    const float4* x4 = (const float4*)fin;
    const float4* Wi = (const float4*)(W + (size_t)j * MAPD);
    const float4* Wg = (const float4*)(W + (size_t)(2 * H + j) * MAPD);
    const float4* Wo = (const float4*)(W + (size_t)(3 * H + j) * MAPD);
    float si = 0.f, sg = 0.f, so = 0.f;
#pragma unroll
    for (int it = 0; it < 8; ++it) {
        int idx = it * 64 + lane;
        float4 xv = x4[idx];
        float4 a = Wi[idx];
        si += a.x * xv.x + a.y * xv.y + a.z * xv.z + a.w * xv.w;
        float4 g = Wg[idx];
        sg += g.x * xv.x + g.y * xv.y + g.z * xv.z + g.w * xv.w;
        float4 o = Wo[idx];
        so += o.x * xv.x + o.y * xv.y + o.z * xv.z + o.w * xv.w;
    }
    si = wave_reduce_sum(si);
    sg = wave_reduce_sum(sg);
    so = wave_reduce_sum(so);
    if (lane == 0) {
        float gi = si + b_ih[j] + b_hh[j];
        float gg = sg + b_ih[2 * H + j] + b_hh[2 * H + j];
        float go = so + b_ih[3 * H + j] + b_hh[3 * H + j];
        float c = sigmoidf_(gi) * tanhf(gg);
        h1[j] = sigmoidf_(go) * tanhf(c);
    }
}

// Kernel 3: fc  out[r] = h1 . fc_w[r] + fc_b[r],  r = 0,1
__global__ __launch_bounds__(128) void k_fc(
    const float* __restrict__ h1,     // ws + 2048
    const float* __restrict__ fcw,    // [2][1024]
    const float* __restrict__ fcb,    // [2]
    float* __restrict__ out)          // [2]
{
    int wave = threadIdx.x >> 6;
    int lane = threadIdx.x & 63;
    float s = 0.f;
#pragma unroll
    for (int k = 0; k < 16; ++k) {
        int idx = k * 64 + lane;
        s += h1[idx] * fcw[wave * H + idx];
    }
    s = wave_reduce_sum(s);
    if (lane == 0) out[wave] = s + fcb[wave];
}

extern "C" void kernel_launch(void* const* d_in, const int* in_sizes, int n_in,
                              void* d_out, int out_size, void* d_ws, size_t ws_size,
                              hipStream_t stream) {
    const float* goal    = (const float*)d_in[0];
    const float* cur     = (const float*)d_in[1];
    const float* map     = (const float*)d_in[2];
    const float* W_ih_map = (const float*)d_in[3];
    // d_in[4] = W_hh_map  (unused: h0 = 0)
    const float* b_ih_map = (const float*)d_in[5];
    const float* b_hh_map = (const float*)d_in[6];
    const float* W_ih_pts = (const float*)d_in[7];
    // d_in[8] = W_hh_pts  (unused)
    const float* b_ih_pts = (const float*)d_in[9];
    const float* b_hh_pts = (const float*)d_in[10];
    const float* W_ih_1  = (const float*)d_in[11];
    // d_in[12] = W_hh_1   (unused)
    const float* b_ih_1  = (const float*)d_in[13];
    const float* b_hh_1  = (const float*)d_in[14];
    const float* fc_w    = (const float*)d_in[15];
    const float* fc_b    = (const float*)d_in[16];

    float* ws  = (float*)d_ws;          // [0..2047] final_in, [2048..3071] h1
    float* out = (float*)d_out;

    k_first<<<257, 256, 0, stream>>>(map, W_ih_map, b_ih_map, b_hh_map,
                                     W_ih_pts, b_ih_pts, b_hh_pts,
                                     goal, cur, ws);
    k_lstm1<<<256, 256, 0, stream>>>(ws, W_ih_1, b_ih_1, b_hh_1, ws + 2048);
    k_fc<<<1, 128, 0, stream>>>(ws + 2048, fc_w, fc_b, out);
}